// Round 4
// baseline (336.616 us; speedup 1.0000x reference)
//
#include <hip/hip_runtime.h>

// WadaIN modulated conv1d — round 8: batch-independent weights.
// Identity: out = leaky( dm[b,o] * sum_{i,k} w[o,i,k] * (x[b,i,t+k-2]*s[b,i]) )
//   dm[b,o] = rsqrt( sum_i s[b,i]^2 * sum_k w[o,i,k]^2 + 1e-8 )  (== reference)
// So the bf16 conv weight image is BATCH-INDEPENDENT (655 KB, written once by
// 32 blocks) instead of per-batch (10.5 MB, 512 blocks). s folds into x during
// staging f2bf; dm folds into the epilogue. prep collapses to ONE 48-block
// kernel (32 wconv blocks + 16 style/dm blocks), one fewer launch.
// R0-R3 evidence: conv invariant at 132us; ~185us non-conv time invariant
// under matvec restructures -> the 512-block prep shell itself was the cost.
// conv schedule UNCHANGED from ws3 (132us) except s-mul + dm-epilogue.

#define B_    16
#define CIN   256
#define COUT  256
#define KW    5
#define SPK   128
#define TT    8192

#define OM    128   // o per block
#define TN    256   // t per block (fast kernel)
#define BI    32    // input channels per K-chunk
#define NCH   (CIN / BI)   // 8

#define XROWS 264                                  // 260 used (TN + 4 halo)
#define WSLAB (KW * OM * 32)                       // 20480 ushorts per (ot,ch)
#define WBF_BYTES ((size_t)2 * NCH * WSLAB * 2)    // 655,360 B (batch-indep!)
#define S_OFF   WBF_BYTES
#define DM_OFF  (WBF_BYTES + (size_t)B_ * CIN * 4)
#define WS_NEED (WBF_BYTES + (size_t)B_ * CIN * 4 * 2)   // 688,128 B

typedef __attribute__((ext_vector_type(8))) short short8;
typedef __attribute__((ext_vector_type(4))) float f32x4;
typedef unsigned short ushort_t;
typedef unsigned int uint_t;

__device__ __forceinline__ ushort_t f2bf(float f) {
    uint_t u = __float_as_uint(f);
    u += 0x7FFF + ((u >> 16) & 1);   // RNE
    return (ushort_t)(u >> 16);
}

// ---------------------------------------------------------------------------
// prep2: grid(48), 256 thr.
//   blocks 0..31  : og = blockIdx -> bf16-convert 8 output rows of weight into
//                   conv-LDS layout, PRE-SWIZZLED ((g ^ (o_l>>1)&3) 16B slots).
//   blocks 32..47 : b = blockIdx-32 -> s[b,:] = c@W^T + bias ; dm[b,:] via
//                   dm[b,o] = rsqrt(sum_i s^2 * sum_k w[o,i,k]^2 + 1e-8).
__global__ __launch_bounds__(256) void prep2_kernel(
    const float* __restrict__ c_trg, const float* __restrict__ style_w,
    const float* __restrict__ style_b, const float* __restrict__ weight,
    ushort_t* __restrict__ wbf, float* __restrict__ s_glob,
    float* __restrict__ dm_glob)
{
    __shared__ float sm[8 * 1280];      // 40 KB (wconv path)
    __shared__ float c_sh[SPK];
    __shared__ float s2_sh[CIN];

    const int tid = threadIdx.x;

    if (blockIdx.x < 32) {
        // ---- weight -> bf16 swizzled slabs (batch-independent) ----
        const int og = blockIdx.x;
        const float* wsrc = weight + (size_t)og * 8 * 1280;
        #pragma unroll
        for (int it = 0; it < 10; ++it)
            *(float4*)&sm[(it * 256 + tid) * 4] = *(const float4*)&wsrc[(it * 256 + tid) * 4];
        __syncthreads();

        for (int r = tid; r < 320; r += 256) {
            const int oi  = r / 40;
            const int rem = r - oi * 40;
            const int ch  = rem / 5;
            const int k   = rem - ch * 5;
            const int o   = og * 8 + oi;
            const int ot  = o >> 7;
            const int o_l = o & 127;
            const int swz = (o_l >> 1) & 3;
            ushort_t* dst = wbf + (((size_t)(ot * NCH + ch) * KW + k) * OM + o_l) * 32;
            #pragma unroll
            for (int g = 0; g < 4; ++g) {
                union { ushort_t us[8]; uint4 v; } pk;
                #pragma unroll
                for (int ii = 0; ii < 8; ++ii) {
                    int i_g = ch * 32 + g * 8 + ii;
                    pk.us[ii] = f2bf(sm[oi * 1280 + i_g * 5 + k]);
                }
                *(uint4*)&dst[(g ^ swz) * 8] = pk.v;
            }
        }
    } else {
        // ---- style + demod for one batch ----
        const int b = blockIdx.x - 32;
        if (tid < SPK) c_sh[tid] = c_trg[b * SPK + tid];
        __syncthreads();

        float acc = style_b[tid];
        const float* wr = style_w + (size_t)tid * SPK;
        #pragma unroll 4
        for (int j = 0; j < SPK; ++j) acc += c_sh[j] * wr[j];
        s_glob[b * CIN + tid] = acc;
        s2_sh[tid] = acc * acc;
        __syncthreads();

        // dm[b][o=tid]: stream weight row o (1280 floats, float4-aligned)
        const float* wo = weight + (size_t)tid * 1280;
        float a = 0.f;
        #pragma unroll 4
        for (int ig = 0; ig < 64; ++ig) {
            float q[20];
            #pragma unroll
            for (int f = 0; f < 5; ++f)
                *(float4*)&q[f * 4] = *(const float4*)&wo[ig * 20 + f * 4];
            #pragma unroll
            for (int c = 0; c < 4; ++c) {
                const float s2 = s2_sh[ig * 4 + c];
                #pragma unroll
                for (int k = 0; k < 5; ++k) {
                    const float v = q[c * 5 + k];
                    a += v * v * s2;
                }
            }
        }
        dm_glob[b * COUT + tid] = rsqrtf(a + 1e-8f);
    }
}

// ---------------------------------------------------------------------------
// fast conv: ws3 schedule verbatim, plus: batch-indep wbf base, s folded into
// x staging (mul before f2bf), dm folded into epilogue.
__global__ __launch_bounds__(512, 2) void conv_mfma_ws4_kernel(
    const float* __restrict__ x, const ushort_t* __restrict__ wbf,
    const float* __restrict__ s_glob, const float* __restrict__ dm_glob,
    float* __restrict__ out)
{
    __shared__ __align__(16) ushort_t w_sh[2][WSLAB];    // 2 x 40960 B
    __shared__ __align__(16) ushort_t x_sh[XROWS * 32];  // 16896 B
    __shared__ float s_lds[CIN];                          // 1 KB
    __shared__ float dm_lds[OM];                          // 512 B

    const int b   = blockIdx.z;
    const int ot  = blockIdx.y;
    const int o0  = ot * OM;
    const int t0  = blockIdx.x * TN;
    const int tid = threadIdx.x;

    const int lane  = tid & 63;
    const int wv    = tid >> 6;      // 0..7
    const int wm    = wv >> 2;       // 0..1  (o half)
    const int wn    = wv & 3;        // 0..3  (t quarter)
    const int col16 = lane & 15;
    const int quad  = lane >> 4;

    const int rl = lane;
    const int i4 = wv;

    f32x4 acc[4][4];
    #pragma unroll
    for (int mt = 0; mt < 4; ++mt)
        #pragma unroll
        for (int nt = 0; nt < 4; ++nt)
            acc[mt][nt] = (f32x4){0.f, 0.f, 0.f, 0.f};

    const float* xb = x + (size_t)b * CIN * TT;
    const ushort_t* wslab = wbf + (size_t)ot * NCH * WSLAB;   // batch-indep

    float xr0[20], xr1[20];          // ping-pong x staging, STATIC indexing only

#define STAGE_W(CH, BUF) do {                                                  \
        const ushort_t* ws_ = wslab + (size_t)(CH) * WSLAB;                    \
        _Pragma("unroll")                                                      \
        for (int s_ = 0; s_ < 5; ++s_) {                                       \
            const int off_ = s_ * 4096 + wv * 512;   /* ushort units */        \
            __builtin_amdgcn_global_load_lds(                                  \
                (const __attribute__((address_space(1))) uint_t*)(ws_ + off_ + lane * 8), \
                (__attribute__((address_space(3))) uint_t*)(&w_sh[BUF][off_]), \
                16, 0, 0);                                                     \
        }                                                                      \
    } while (0)

#define LOAD_X(CH, XR) do {                                                    \
        const float* xp_ = xb + (size_t)((CH) * BI + i4 * 4) * TT;             \
        _Pragma("unroll")                                                      \
        for (int rd_ = 0; rd_ < 5; ++rd_) {                                    \
            int r_ = rd_ * 64 + rl;                                            \
            if (r_ < 260) {                                                    \
                int tg_ = t0 + r_ - 2;                                         \
                tg_ = (tg_ < 0) ? -tg_ : tg_;                                  \
                tg_ = (tg_ > TT - 1) ? (2 * (TT - 1) - tg_) : tg_;             \
                XR[rd_ * 4 + 0] = xp_[tg_];                                    \
                XR[rd_ * 4 + 1] = xp_[TT + tg_];                               \
                XR[rd_ * 4 + 2] = xp_[2 * TT + tg_];                           \
                XR[rd_ * 4 + 3] = xp_[3 * TT + tg_];                           \
            }                                                                  \
        }                                                                      \
    } while (0)

// s folded here: x*s before f2bf (s_lds staged once at kernel start)
#define PUT_X(CH, XR) do {                                                     \
        const float s0_ = s_lds[(CH) * BI + i4 * 4 + 0];                       \
        const float s1_ = s_lds[(CH) * BI + i4 * 4 + 1];                       \
        const float s2_ = s_lds[(CH) * BI + i4 * 4 + 2];                       \
        const float s3_ = s_lds[(CH) * BI + i4 * 4 + 3];                       \
        _Pragma("unroll")                                                      \
        for (int rd_ = 0; rd_ < 5; ++rd_) {                                    \
            int r_ = rd_ * 64 + rl;                                            \
            if (r_ < 260) {                                                    \
                union { ushort_t us[4]; uint2 u2; } p_;                        \
                p_.us[0] = f2bf(XR[rd_ * 4 + 0] * s0_);                        \
                p_.us[1] = f2bf(XR[rd_ * 4 + 1] * s1_);                        \
                p_.us[2] = f2bf(XR[rd_ * 4 + 2] * s2_);                        \
                p_.us[3] = f2bf(XR[rd_ * 4 + 3] * s3_);                        \
                int grp_ = (i4 >> 1) ^ ((r_ ^ (r_ >> 2)) & 3);                 \
                *(uint2*)&x_sh[r_ * 32 + grp_ * 8 + (i4 & 1) * 4] = p_.u2;     \
            }                                                                  \
        }                                                                      \
    } while (0)

#define MFMA_CHUNK(BUF) do {                                                   \
        _Pragma("unroll")                                                      \
        for (int kt_ = 0; kt_ < KW; ++kt_) {                                   \
            short8 a_[4], bf_[4];                                              \
            _Pragma("unroll")                                                  \
            for (int mt_ = 0; mt_ < 4; ++mt_) {                                \
                const int row_  = kt_ * OM + wm * 64 + mt_ * 16 + col16;       \
                const int slot_ = quad ^ ((row_ >> 1) & 3);                    \
                a_[mt_] = *(const short8*)&w_sh[BUF][row_ * 32 + slot_ * 8];   \
            }                                                                  \
            _Pragma("unroll")                                                  \
            for (int nt_ = 0; nt_ < 4; ++nt_) {                                \
                const int r_   = wn * 64 + nt_ * 16 + col16 + kt_;             \
                const int grp_ = quad ^ ((r_ ^ (r_ >> 2)) & 3);                \
                bf_[nt_] = *(const short8*)&x_sh[r_ * 32 + grp_ * 8];          \
            }                                                                  \
            _Pragma("unroll")                                                  \
            for (int mt_ = 0; mt_ < 4; ++mt_)                                  \
                _Pragma("unroll")                                              \
                for (int nt_ = 0; nt_ < 4; ++nt_)                              \
                    acc[mt_][nt_] = __builtin_amdgcn_mfma_f32_16x16x32_bf16(   \
                        a_[mt_], bf_[nt_], acc[mt_][nt_], 0, 0, 0);            \
        }                                                                      \
    } while (0)

#define CHUNK_BODY(CH, CUR, NXT, XR_CUR, XR_NXT) do {                          \
        PUT_X(CH, XR_CUR);                                                     \
        __syncthreads();                                                       \
        if ((CH) < NCH - 1) {                                                  \
            STAGE_W((CH) + 1, NXT);                                            \
            LOAD_X((CH) + 1, XR_NXT);                                          \
        }                                                                      \
        __builtin_amdgcn_sched_barrier(0);                                     \
        MFMA_CHUNK(CUR);                                                       \
        if ((CH) < NCH - 1)                                                    \
            __syncthreads();                                                   \
    } while (0)

    // stage s/dm rows + prologue loads, then one barrier for s_lds visibility
    if (tid < CIN) s_lds[tid] = s_glob[b * CIN + tid];
    if (tid < OM)  dm_lds[tid] = dm_glob[b * COUT + o0 + tid];
    STAGE_W(0, 0);
    LOAD_X(0, xr0);
    __syncthreads();

    CHUNK_BODY(0, 0, 1, xr0, xr1);
    CHUNK_BODY(1, 1, 0, xr1, xr0);
    CHUNK_BODY(2, 0, 1, xr0, xr1);
    CHUNK_BODY(3, 1, 0, xr1, xr0);
    CHUNK_BODY(4, 0, 1, xr0, xr1);
    CHUNK_BODY(5, 1, 0, xr1, xr0);
    CHUNK_BODY(6, 0, 1, xr0, xr1);
    CHUNK_BODY(7, 1, 0, xr1, xr0);

#undef STAGE_W
#undef LOAD_X
#undef PUT_X
#undef MFMA_CHUNK
#undef CHUNK_BODY

    // epilogue: dm + leaky relu + store
    #pragma unroll
    for (int mt = 0; mt < 4; ++mt) {
        #pragma unroll
        for (int nt = 0; nt < 4; ++nt) {
            const int t_o = t0 + wn * 64 + nt * 16 + col16;
            #pragma unroll
            for (int reg = 0; reg < 4; ++reg) {
                const int o_l = wm * 64 + mt * 16 + quad * 4 + reg;
                float v = acc[mt][nt][reg] * dm_lds[o_l];
                v = (v > 0.f) ? v : 0.2f * v;
                out[((size_t)(b * COUT + o0 + o_l)) * TT + t_o] = v;
            }
        }
    }
}

// ---------------------------------------------------------------------------
// Fallback: R3 kernel verbatim (no workspace), known-good at ~419 us.
__global__ __launch_bounds__(256, 3) void conv_mfma_fb_kernel(
    const float* __restrict__ x, const float* __restrict__ c_trg,
    const float* __restrict__ style_w, const float* __restrict__ style_b,
    const float* __restrict__ weight, float* __restrict__ out)
{
    __shared__ ushort_t x_sh[136 * 32];
    __shared__ ushort_t w_sh[KW * 128 * 32];
    __shared__ float    c_sh[SPK];
    __shared__ float    s_sh[CIN];
    __shared__ float    dm_acc[128];
    __shared__ float    dmv[128];

    const int b   = blockIdx.z;
    const int o0  = blockIdx.y * 128;
    const int t0  = blockIdx.x * 128;
    const int tid = threadIdx.x;

    const int lane  = tid & 63;
    const int wvv   = tid >> 6;
    const int wm    = wvv >> 1;
    const int wn    = wvv & 1;
    const int col16 = lane & 15;
    const int quad  = lane >> 4;

    if (tid < SPK) c_sh[tid] = c_trg[b * SPK + tid];
    if (tid < 128) dm_acc[tid] = 0.f;
    __syncthreads();
    {
        float acc = style_b[tid];
        const float* wr = style_w + (size_t)tid * SPK;
        #pragma unroll 4
        for (int j = 0; j < SPK; ++j) acc += c_sh[j] * wr[j];
        s_sh[tid] = acc;
    }

    f32x4 acc[4][4];
    #pragma unroll
    for (int mt = 0; mt < 4; ++mt)
        #pragma unroll
        for (int nt = 0; nt < 4; ++nt)
            acc[mt][nt] = (f32x4){0.f, 0.f, 0.f, 0.f};

    const float* xb = x + (size_t)b * CIN * TT;

    for (int ch = 0; ch < NCH; ++ch) {
        const int i0 = ch * BI;
        __syncthreads();
        {
            const int i4s = tid >> 5;
            const int rls = tid & 31;
            const float* xp = xb + (size_t)(i0 + i4s * 4) * TT;
            #pragma unroll
            for (int rr = 0; rr < 136; rr += 32) {
                int r = rr + rls;
                if (r < 136) {
                    int tg = t0 + r - 2;
                    tg = (tg < 0) ? -tg : tg;
                    tg = (tg > TT - 1) ? (2 * (TT - 1) - tg) : tg;
                    float v0 = xp[tg];
                    float v1 = xp[TT + tg];
                    float v2 = xp[2 * TT + tg];
                    float v3 = xp[3 * TT + tg];
                    union { ushort_t us[4]; uint2 u2; } p;
                    p.us[0] = f2bf(v0); p.us[1] = f2bf(v1);
                    p.us[2] = f2bf(v2); p.us[3] = f2bf(v3);
                    int grp = (i4s >> 1) ^ (r & 3);
                    *(uint2*)&x_sh[r * 32 + grp * 8 + (i4s & 1) * 4] = p.u2;
                }
            }
        }
        {
            const int i4s = tid & 7;
            #pragma unroll
            for (int pass = 0; pass < 4; ++pass) {
                const int o_l = (tid >> 3) + pass * 32;
                const float* wp = weight + ((size_t)(o0 + o_l) * CIN + i0 + i4s * 4) * KW;
                float q[20];
                #pragma unroll
                for (int f = 0; f < 5; ++f)
                    *(float4*)&q[f * 4] = *(const float4*)(wp + f * 4);
                float sv0 = s_sh[i0 + i4s * 4 + 0];
                float sv1 = s_sh[i0 + i4s * 4 + 1];
                float sv2 = s_sh[i0 + i4s * 4 + 2];
                float sv3 = s_sh[i0 + i4s * 4 + 3];
                float m0[5], m1[5], m2[5], m3[5];
                float psum = 0.f;
                #pragma unroll
                for (int k = 0; k < 5; ++k) {
                    m0[k] = q[0 * 5 + k] * sv0;  psum += m0[k] * m0[k];
                    m1[k] = q[1 * 5 + k] * sv1;  psum += m1[k] * m1[k];
                    m2[k] = q[2 * 5 + k] * sv2;  psum += m2[k] * m2[k];
                    m3[k] = q[3 * 5 + k] * sv3;  psum += m3[k] * m3[k];
                }
                atomicAdd(&dm_acc[o_l], psum);
                #pragma unroll
                for (int k = 0; k < 5; ++k) {
                    union { ushort_t us[4]; uint2 u2; } p;
                    p.us[0] = f2bf(m0[k]); p.us[1] = f2bf(m1[k]);
                    p.us[2] = f2bf(m2[k]); p.us[3] = f2bf(m3[k]);
                    *(uint2*)&w_sh[(k * 128 + o_l) * 32 + i4s * 4] = p.u2;
                }
            }
        }
        __syncthreads();
        #pragma unroll
        for (int kt = 0; kt < KW; ++kt) {
            short8 a[4], bf[4];
            #pragma unroll
            for (int mt = 0; mt < 4; ++mt)
                a[mt] = *(const short8*)&w_sh[(kt * 128 + wm * 64 + mt * 16 + col16) * 32 + quad * 8];
            #pragma unroll
            for (int nt = 0; nt < 4; ++nt) {
                int r   = wn * 64 + nt * 16 + col16 + kt;
                int grp = quad ^ (r & 3);
                bf[nt] = *(const short8*)&x_sh[r * 32 + grp * 8];
            }
            #pragma unroll
            for (int mt = 0; mt < 4; ++mt)
                #pragma unroll
                for (int nt = 0; nt < 4; ++nt)
                    acc[mt][nt] = __builtin_amdgcn_mfma_f32_16x16x32_bf16(
                        a[mt], bf[nt], acc[mt][nt], 0, 0, 0);
        }
    }

    __syncthreads();
    if (tid < 128) dmv[tid] = rsqrtf(dm_acc[tid] + 1e-8f);
    __syncthreads();

    #pragma unroll
    for (int mt = 0; mt < 4; ++mt) {
        #pragma unroll
        for (int nt = 0; nt < 4; ++nt) {
            const int t_o = t0 + wn * 64 + nt * 16 + col16;
            #pragma unroll
            for (int reg = 0; reg < 4; ++reg) {
                const int o_l = wm * 64 + mt * 16 + quad * 4 + reg;
                float v = acc[mt][nt][reg] * dmv[o_l];
                v = (v > 0.f) ? v : 0.2f * v;
                out[((size_t)(b * COUT + o0 + o_l)) * TT + t_o] = v;
            }
        }
    }
}

// ---------------------------------------------------------------------------
extern "C" void kernel_launch(void* const* d_in, const int* in_sizes, int n_in,
                              void* d_out, int out_size, void* d_ws, size_t ws_size,
                              hipStream_t stream)
{
    const float* x       = (const float*)d_in[0];
    const float* c_trg   = (const float*)d_in[1];
    const float* style_w = (const float*)d_in[2];
    const float* style_b = (const float*)d_in[3];
    const float* weight  = (const float*)d_in[4];
    float* out = (float*)d_out;

    if (ws_size >= WS_NEED) {
        ushort_t* wbf   = (ushort_t*)d_ws;
        float* s_glob   = (float*)((char*)d_ws + S_OFF);
        float* dm_glob  = (float*)((char*)d_ws + DM_OFF);
        prep2_kernel<<<dim3(48), dim3(256), 0, stream>>>(
            c_trg, style_w, style_b, weight, wbf, s_glob, dm_glob);
        conv_mfma_ws4_kernel<<<dim3(TT / TN, COUT / OM, B_), dim3(512), 0, stream>>>(
            x, wbf, s_glob, dm_glob, out);
    } else {
        conv_mfma_fb_kernel<<<dim3(TT / 128, COUT / 128, B_), dim3(256), 0, stream>>>(
            x, c_trg, style_w, style_b, weight, out);
    }

    hipMemcpyAsync(out + (size_t)B_ * COUT * TT, c_trg,
                   (size_t)B_ * SPK * sizeof(float),
                   hipMemcpyDeviceToDevice, stream);
}